// Round 5
// baseline (344.775 us; speedup 1.0000x reference)
//
#include <hip/hip_runtime.h>

// ---------------------------------------------------------------------------
// AttentionHead: B=4, C=256, N=4096, QK=64. Column-softmax attention.
// convert -> proj (QKV) -> colsum (partial col sums of 2^S) -> lrs (finalize)
// -> attn (S->P in LDS -> PV; i-tile 64, channel-split cc=4, XCD-pinned,
//    simple 2-barrier steps, loads issued ahead of the S chain) -> mlp.
// Workspace: 21,757,952 bytes.
// ---------------------------------------------------------------------------

typedef unsigned short u16;
typedef unsigned int u32;
typedef __attribute__((ext_vector_type(2))) unsigned int u32x2;
typedef __attribute__((ext_vector_type(8))) unsigned short ushort8;
typedef __attribute__((ext_vector_type(8))) __bf16 bf16x8;
typedef __attribute__((ext_vector_type(4))) float f32x4;

#define MFMA16(a, b, c) __builtin_amdgcn_mfma_f32_16x16x32_bf16((a), (b), (c), 0, 0, 0)
#define QSCALE 0.18033688011112042f  // 0.125 * log2(e)

__device__ __forceinline__ u16 f2bf(float f) {  // round-to-nearest-even
  u32 u = __builtin_bit_cast(u32, f);
  u += 0x7FFFu + ((u >> 16) & 1u);
  return (u16)(u >> 16);
}
__device__ __forceinline__ u32 pack2(float lo, float hi) {  // 2 bf16 (trunc)
  u32 a = __builtin_bit_cast(u32, lo), b = __builtin_bit_cast(u32, hi);
  return (a >> 16) | (b & 0xffff0000u);
}
__device__ __forceinline__ bf16x8 ld8(const u16* p) {
  return __builtin_bit_cast(bf16x8, *reinterpret_cast<const ushort8*>(p));
}
__device__ __forceinline__ f32x4 fz4() {
  f32x4 z = {0.f, 0.f, 0.f, 0.f};
  return z;
}

// ---- convert all weight matrices fp32 -> bf16 -----------------------------
__global__ __launch_bounds__(256) void k_convert(
    const float* __restrict__ wq, const float* __restrict__ wk,
    const float* __restrict__ wv, const float* __restrict__ w1,
    const float* __restrict__ w2, u16* __restrict__ dq, u16* __restrict__ dk,
    u16* __restrict__ dv, u16* __restrict__ d1, u16* __restrict__ d2) {
  int i = blockIdx.x * 256 + threadIdx.x;
  if (i < 16384)       dq[i]          = f2bf(wq[i]);
  else if (i < 32768)  dk[i - 16384]  = f2bf(wk[i - 16384]);
  else if (i < 98304)  dv[i - 32768]  = f2bf(wv[i - 32768]);
  else if (i < 163840) d1[i - 98304]  = f2bf(w1[i - 98304]);
  else                 d2[i - 163840] = f2bf(w2[i - 163840]);
}

// ---- fused QKV projection, gathers x fp32 [b][c][pos] directly ------------
// i-tile = 16 pos. Q/K: D[pos][o]; V: D[o][pos]. Grid 1024 (b = id&3).
__global__ __launch_bounds__(256, 4) void k_proj(
    const float* __restrict__ x, const u16* __restrict__ wq,
    const float* __restrict__ bQ, const u16* __restrict__ wk,
    const float* __restrict__ bK, const u16* __restrict__ wv,
    const float* __restrict__ bV, const float* __restrict__ PE,
    u16* __restrict__ Qt, u16* __restrict__ Kt, u16* __restrict__ Vc) {
  int b = blockIdx.x & 3, n0 = (blockIdx.x >> 2) * 16;
  int lane = threadIdx.x & 63, wid = threadIdx.x >> 6;
  int l15 = lane & 15, g = lane >> 4;
  const float* xb = x + (size_t)b * 1048576 + n0 + l15;  // + c*4096

  f32x4 aq = fz4(), ak = fz4(), av[4];
#pragma unroll
  for (int m = 0; m < 4; ++m) av[m] = fz4();

  for (int kk = 0; kk < 8; ++kk) {
    int c0 = kk * 32 + 8 * g;
    ushort8 xr;
#pragma unroll
    for (int e = 0; e < 8; ++e) xr[e] = f2bf(xb[(size_t)(c0 + e) * 4096]);
    bf16x8 xa = __builtin_bit_cast(bf16x8, xr);
    bf16x8 fq = ld8(wq + (16 * wid + l15) * 256 + c0);
    bf16x8 fk = ld8(wk + (16 * wid + l15) * 256 + c0);
    aq = MFMA16(xa, fq, aq);
    ak = MFMA16(xa, fk, ak);
#pragma unroll
    for (int m = 0; m < 4; ++m) {
      bf16x8 fv = ld8(wv + (64 * wid + 16 * m + l15) * 256 + c0);
      av[m] = MFMA16(fv, xa, av[m]);
    }
  }
  int o = 16 * wid + l15;
#pragma unroll
  for (int r = 0; r < 4; ++r) {
    int pos = n0 + 4 * g + r;
    float pe = PE[o * 4096 + pos];
    Qt[((size_t)b * 4096 + pos) * 64 + o] = f2bf((aq[r] + bQ[o] + pe) * QSCALE);
    Kt[((size_t)b * 4096 + pos) * 64 + o] = f2bf(ak[r] + bK[o] + pe);
  }
#pragma unroll
  for (int m = 0; m < 4; ++m)
#pragma unroll
    for (int r = 0; r < 4; ++r) {
      int ov = 64 * wid + 16 * m + 4 * g + r;
      int pos = n0 + l15;
      Vc[((size_t)b * 256 + ov) * 4096 + pos] = f2bf(av[m][r] + bV[ov]);
    }
}

// ---- pass 1: partial column sums of 2^S over 4 i-chunks -------------------
// Grid 1024: combo = id&15 -> (ic,b), jt = id>>4. sp[(ic*4+b)*4096 + j].
__global__ __launch_bounds__(256, 4) void k_colsum(const u16* __restrict__ Qt,
                                                   const u16* __restrict__ Kt,
                                                   float* __restrict__ sp) {
  int combo = blockIdx.x & 15, ic = combo >> 2, b = combo & 3;
  int j0 = (blockIdx.x >> 4) * 64;
  int lane = threadIdx.x & 63, wid = threadIdx.x >> 6;
  int l15 = lane & 15, g = lane >> 4;
  const u16* qb = Qt + (size_t)b * 262144;
  const u16* kb = Kt + (size_t)b * 262144;
  int j = j0 + 16 * wid + l15;
  bf16x8 fk0 = ld8(kb + j * 64 + 8 * g);
  bf16x8 fk1 = ld8(kb + j * 64 + 32 + 8 * g);
  float part = 0.f;
  for (int i0 = ic * 1024; i0 < ic * 1024 + 1024; i0 += 64) {
    f32x4 acc[4];
#pragma unroll
    for (int m = 0; m < 4; ++m) {
      const u16* qr = qb + (i0 + 16 * m + l15) * 64;
      acc[m] = fz4();
      acc[m] = MFMA16(ld8(qr + 8 * g), fk0, acc[m]);
      acc[m] = MFMA16(ld8(qr + 32 + 8 * g), fk1, acc[m]);
    }
#pragma unroll
    for (int m = 0; m < 4; ++m)
#pragma unroll
      for (int r = 0; r < 4; ++r) part += exp2f(acc[m][r]);
  }
  part += __shfl_xor(part, 16);
  part += __shfl_xor(part, 32);
  if (g == 0) sp[((size_t)ic * 4 + b) * 4096 + j] = part;
}

// ---- finalize: lrs[b][j] = -log2(sum of 4 partial column sums) ------------
__global__ __launch_bounds__(256) void k_lrs(const float* __restrict__ sp,
                                             float* __restrict__ lrs) {
  int i = blockIdx.x * 1024 + threadIdx.x * 4;  // grid 16
  float4 s0 = *reinterpret_cast<const float4*>(sp + i);
  float4 s1 = *reinterpret_cast<const float4*>(sp + 16384 + i);
  float4 s2 = *reinterpret_cast<const float4*>(sp + 32768 + i);
  float4 s3 = *reinterpret_cast<const float4*>(sp + 49152 + i);
  float4 r;
  r.x = -__log2f(s0.x + s1.x + s2.x + s3.x);
  r.y = -__log2f(s0.y + s1.y + s2.y + s3.y);
  r.z = -__log2f(s0.z + s1.z + s2.z + s3.z);
  r.w = -__log2f(s0.w + s1.w + s2.w + s3.w);
  *reinterpret_cast<float4*>(lrs + i) = r;
}

// ---- pass 2: attention. Grid 1024: b=id&3, cc=(id>>2)&3, it=id>>4. --------
// id&7 -> XCD pin: each XCD sees one b and 2 cc halves (~2.5 MB L2 set).
// S: A=K rows j, B=Q cols i -> lane holds (i=l15, j=4g+r) -> ds_write_b64.
// PV: A=P rows i (b128), B=V rows c. 64 channels/block (1 c-subtile/wave).
__global__ __launch_bounds__(256, 4) void k_attn(
    const u16* __restrict__ Qt, const u16* __restrict__ Kt,
    const u16* __restrict__ Vc, const float* __restrict__ lrs,
    u16* __restrict__ attT) {
  __shared__ u16 P[64][72];
  int id = blockIdx.x;
  int b = id & 3, cc = (id >> 2) & 3, i0 = (id >> 4) * 64;
  int t = threadIdx.x, lane = t & 63, wid = t >> 6;
  int l15 = lane & 15, g = lane >> 4;
  const u16* qb = Qt + (size_t)b * 262144;
  const u16* kb = Kt + (size_t)b * 262144;
  const u16* vrow = Vc + ((size_t)b * 256 + cc * 64 + 16 * wid + l15) * 4096;
  const float* lrb = lrs + b * 4096;

  bf16x8 aq[4][2];  // Q B-frags for this block's 64 i, held all steps
#pragma unroll
  for (int m = 0; m < 4; ++m)
#pragma unroll
    for (int h = 0; h < 2; ++h)
      aq[m][h] = ld8(qb + (i0 + 16 * m + l15) * 64 + h * 32 + 8 * g);

  f32x4 oacc[4];  // lane: i = 16m + 4g + r, c = cc*64 + 16wid + l15
#pragma unroll
  for (int m = 0; m < 4; ++m) oacc[m] = fz4();

  for (int jg = 0; jg < 4096; jg += 64) {
    // issue all global loads for this step up front (latency overlap)
    const u16* kr = kb + (size_t)(jg + 16 * wid + l15) * 64;
    bf16x8 fk0 = ld8(kr + 8 * g);
    bf16x8 fk1 = ld8(kr + 32 + 8 * g);
    float4 lr = *reinterpret_cast<const float4*>(lrb + jg + 16 * wid + 4 * g);
    bf16x8 bv0 = ld8(vrow + jg + 8 * g);
    bf16x8 bv1 = ld8(vrow + jg + 32 + 8 * g);
    // S tile -> P (wave wid owns j-subtile 16*wid)
#pragma unroll
    for (int m = 0; m < 4; ++m) {
      f32x4 s = fz4();
      s = MFMA16(fk0, aq[m][0], s);
      s = MFMA16(fk1, aq[m][1], s);
      u32x2 pw = {pack2(exp2f(s[0] + lr.x), exp2f(s[1] + lr.y)),
                  pack2(exp2f(s[2] + lr.z), exp2f(s[3] + lr.w))};
      *reinterpret_cast<u32x2*>(&P[16 * m + l15][16 * wid + 4 * g]) = pw;
    }
    __syncthreads();
#pragma unroll
    for (int h = 0; h < 2; ++h) {
      bf16x8 bv = h ? bv1 : bv0;
#pragma unroll
      for (int m = 0; m < 4; ++m) {
        bf16x8 ap = ld8(&P[16 * m + l15][h * 32 + 8 * g]);
        oacc[m] = MFMA16(ap, bv, oacc[m]);
      }
    }
    __syncthreads();
  }
  int c = cc * 64 + 16 * wid + l15;
#pragma unroll
  for (int m = 0; m < 4; ++m)
#pragma unroll
    for (int r = 0; r < 4; ++r) {
      int pos = i0 + 16 * m + 4 * g + r;
      attT[((size_t)b * 4096 + pos) * 256 + c] = f2bf(oacc[m][r]);
    }
}

// ---- fused MLP: mish(W1 att + b1) (LDS) -> W2 .. + b2 + x -----------------
// i-tile = 16 pos, grid 1024 (b = id&3). att read directly from global.
__global__ __launch_bounds__(256, 4) void k_mlp(
    const u16* __restrict__ attT, const u16* __restrict__ w1,
    const float* __restrict__ b1, const u16* __restrict__ w2,
    const float* __restrict__ b2, const float* __restrict__ x,
    float* __restrict__ out) {
  __shared__ u16 hdnS[16][264];
  int b = blockIdx.x & 3, n0 = (blockIdx.x >> 2) * 16;
  int lane = threadIdx.x & 63, wid = threadIdx.x >> 6;
  int l15 = lane & 15, g = lane >> 4;
  const u16* arow = attT + ((size_t)b * 4096 + n0) * 256;

  f32x4 h4[4];
#pragma unroll
  for (int n = 0; n < 4; ++n) h4[n] = fz4();
  for (int kk = 0; kk < 8; ++kk) {
    int c0 = kk * 32 + 8 * g;
    bf16x8 am = ld8(arow + l15 * 256 + c0);
#pragma unroll
    for (int n = 0; n < 4; ++n) {
      bf16x8 bn = ld8(w1 + (64 * wid + 16 * n + l15) * 256 + c0);
      h4[n] = MFMA16(am, bn, h4[n]);
    }
  }
#pragma unroll
  for (int n = 0; n < 4; ++n) {
    int hh = 64 * wid + 16 * n + l15;
    float bb = b1[hh];
#pragma unroll
    for (int r = 0; r < 4; ++r) {
      float v = h4[n][r] + bb;
      float sp_ = (v > 15.f) ? v : __logf(1.f + __expf(v));
      float e2 = __expf(-2.f * sp_);
      float th = (1.f - e2) / (1.f + e2);
      hdnS[4 * g + r][hh] = f2bf(v * th);
    }
  }
  __syncthreads();

  f32x4 acc[4];
#pragma unroll
  for (int m = 0; m < 4; ++m) acc[m] = fz4();
  for (int kk = 0; kk < 8; ++kk) {
    int c0 = kk * 32 + 8 * g;
    bf16x8 bn = ld8(&hdnS[l15][c0]);
#pragma unroll
    for (int m = 0; m < 4; ++m) {
      bf16x8 am = ld8(w2 + (64 * wid + 16 * m + l15) * 256 + c0);
      acc[m] = MFMA16(am, bn, acc[m]);
    }
  }
#pragma unroll
  for (int m = 0; m < 4; ++m)
#pragma unroll
    for (int r = 0; r < 4; ++r) {
      int o = 64 * wid + 16 * m + 4 * g + r;
      int pos = n0 + l15;
      size_t idx = ((size_t)b * 256 + o) * 4096 + pos;
      out[idx] = acc[m][r] + b2[o] + x[idx];
    }
}

// ---- workspace layout (bytes) ---------------------------------------------
#define WS_QT 0u          //  2,097,152  Qt  [4][4096][64]  bf16 (pre-scaled)
#define WS_KT 2097152u    //  2,097,152  Kt  [4][4096][64]  bf16
#define WS_VC 4194304u    //  8,388,608  Vc  [4][256][4096] bf16
#define WS_SP 12582912u   //    262,144  sp  [4 ic][4 b][4096] fp32
#define WS_ATT 12845056u  //  8,388,608  attT[4][4096][256] bf16
#define WS_WQ 21233664u   //     32,768
#define WS_WK 21266432u   //     32,768
#define WS_WV 21299200u   //    131,072
#define WS_W1 21430272u   //    131,072
#define WS_W2 21561344u   //    131,072
#define WS_LRS 21692416u  //     65,536  lrs [4 b][4096] fp32  (end: 21,757,952)

extern "C" void kernel_launch(void* const* d_in, const int* in_sizes, int n_in,
                              void* d_out, int out_size, void* d_ws, size_t ws_size,
                              hipStream_t stream) {
  (void)in_sizes; (void)n_in; (void)out_size; (void)ws_size;
  const float* x  = (const float*)d_in[0];
  const float* WQ = (const float*)d_in[1];
  const float* bQ = (const float*)d_in[2];
  const float* WK = (const float*)d_in[3];
  const float* bK = (const float*)d_in[4];
  const float* WV = (const float*)d_in[5];
  const float* bV = (const float*)d_in[6];
  const float* PE = (const float*)d_in[7];
  const float* W1 = (const float*)d_in[8];
  const float* b1 = (const float*)d_in[9];
  const float* W2 = (const float*)d_in[10];
  const float* b2 = (const float*)d_in[11];
  float* out = (float*)d_out;
  char* ws = (char*)d_ws;

  u16* Qt    = (u16*)(ws + WS_QT);
  u16* Kt    = (u16*)(ws + WS_KT);
  u16* Vc    = (u16*)(ws + WS_VC);
  float* sp  = (float*)(ws + WS_SP);
  u16* attT  = (u16*)(ws + WS_ATT);
  u16* wqB   = (u16*)(ws + WS_WQ);
  u16* wkB   = (u16*)(ws + WS_WK);
  u16* wvB   = (u16*)(ws + WS_WV);
  u16* w1B   = (u16*)(ws + WS_W1);
  u16* w2B   = (u16*)(ws + WS_W2);
  float* lrs = (float*)(ws + WS_LRS);

  k_convert<<<896, 256, 0, stream>>>(WQ, WK, WV, W1, W2, wqB, wkB, wvB, w1B, w2B);
  k_proj<<<1024, 256, 0, stream>>>(x, wqB, bQ, wkB, bK, wvB, bV, PE, Qt, Kt, Vc);
  k_colsum<<<1024, 256, 0, stream>>>(Qt, Kt, sp);
  k_lrs<<<16, 256, 0, stream>>>(sp, lrs);
  k_attn<<<1024, 256, 0, stream>>>(Qt, Kt, Vc, lrs, attT);
  k_mlp<<<1024, 256, 0, stream>>>(attT, w1B, b1, w2B, b2, x, out);
}